// Round 1
// baseline (288.728 us; speedup 1.0000x reference)
//
#include <hip/hip_runtime.h>
#include <stdint.h>
#include <math.h>

#define SLEN 2048
#define EPT 8
#define NTHREADS 256
#define TOKENS_PER_OUT 8388608   // 1024*4*2048

// ---------- Threefry-2x32, 20 rounds, matches jax._src.prng ----------
__host__ __device__ __forceinline__ void tf2x32(uint32_t k0, uint32_t k1,
                                                uint32_t x0, uint32_t x1,
                                                uint32_t &o0, uint32_t &o1) {
  uint32_t ks2 = 0x1BD11BDAu ^ k0 ^ k1;
  x0 += k0; x1 += k1;
#define TFR(r) { x0 += x1; x1 = (x1 << (r)) | (x1 >> (32 - (r))); x1 ^= x0; }
  TFR(13) TFR(15) TFR(26) TFR(6)
  x0 += k1;  x1 += ks2 + 1u;
  TFR(17) TFR(29) TFR(16) TFR(24)
  x0 += ks2; x1 += k0 + 2u;
  TFR(13) TFR(15) TFR(26) TFR(6)
  x0 += k0;  x1 += k1 + 3u;
  TFR(17) TFR(29) TFR(16) TFR(24)
  x0 += k1;  x1 += ks2 + 4u;
  TFR(13) TFR(15) TFR(26) TFR(6)
  x0 += ks2; x1 += k0 + 5u;
#undef TFR
  o0 = x0; o1 = x1;
}

// bits -> float in [0,1): (bits>>9 | 1.0f_bits) as float - 1.0  (jax _uniform)
__device__ __forceinline__ float u01_from_bits(uint32_t bits) {
  return __uint_as_float((bits >> 9) | 0x3F800000u) - 1.0f;
}

// correctly-rounded f32 log via f64 (within <=1 ulp of any sane ref impl)
__device__ __forceinline__ float log_cr(float x) {
  return (float)::log((double)x);
}

// XLA ErfInv f32 expander (Giles poly), log1p per ElementalIrEmitter::EmitLog1p
__device__ float erfinv_xla(float x) {
#pragma clang fp contract(off)
  float x2  = x * x;
  float nx2 = -x2;
  float l1p;
  if (fabsf(nx2) < 1e-4f) {
    l1p = (-0.5f * nx2 + 1.0f) * nx2;       // x*(1 - x/2)
  } else {
    l1p = log_cr(1.0f + nx2);               // log(1+x) with the f32 add
  }
  float w = -l1p;
  float p;
  if (w < 5.0f) {
    float ww = w - 2.5f;
    p = 2.81022636e-08f;
    p = p * ww + 3.43273939e-07f;
    p = p * ww + -3.5233877e-06f;
    p = p * ww + -4.39150654e-06f;
    p = p * ww + 0.00021858087f;
    p = p * ww + -0.00125372503f;
    p = p * ww + -0.00417768164f;
    p = p * ww + 0.246640727f;
    p = p * ww + 1.50140941f;
  } else {
    float ww = sqrtf(w) - 3.0f;
    p = -0.000200214257f;
    p = p * ww + 0.000100950558f;
    p = p * ww + 0.00134934322f;
    p = p * ww + -0.00367342844f;
    p = p * ww + 0.00573950773f;
    p = p * ww + -0.0076224613f;
    p = p * ww + 0.00943887047f;
    p = p * ww + 1.00167406f;
    p = p * ww + 2.83297682f;
  }
  return p * x;
}

__global__ __launch_bounds__(NTHREADS)
void gumbel_topk_mask(const float* __restrict__ wfull,   // (B,C,2S) f32
                      const int*   __restrict__ attn,    // (B,C,S) i32
                      const int*   __restrict__ ids,     // (B,C,S) i32
                      int* __restrict__ out,             // 3x(B,C,S) i32 concat
                      uint32_t kg0, uint32_t kg1, uint32_t kn0, uint32_t kn1) {
#pragma clang fp contract(off)
  const int row = blockIdx.x;     // 0..4095 = b*4 + c
  const int t   = threadIdx.x;

  __shared__ uint32_t mk[SLEN];        // order-preserving mapped keys
  __shared__ uint32_t hist[256];
  __shared__ uint32_t tscan[NTHREADS];
  __shared__ int      asum_s;
  __shared__ int      kk_s;
  __shared__ uint32_t prefix_s;
  __shared__ uint32_t remaining_s;

  if (t == 0) asum_s = 0;
  __syncthreads();

  const size_t rbase = (size_t)row * SLEN;
  const size_t wbase = (size_t)row * (2 * SLEN);

  // ---- phase 1: attention-sum partials + per-position keys into LDS ----
  int psum = 0;
  for (int e = 0; e < EPT; ++e) {
    int s = t + NTHREADS * e;                 // coalesced
    psum += attn[rbase + s];

    // gumbel bits (partitionable): counts (hi=0, lo=flat_j), bits = o0^o1
    uint32_t o0, o1;
    tf2x32(kg0, kg1, 0u, (uint32_t)(rbase + s), o0, o1);
    uint32_t b = o0 ^ o1;
    float f  = u01_from_bits(b);
    // uniform(minval=tiny, maxval=1): floats*(1-tiny=1.0f) + tiny, then max
    float uu = fmaxf(1.17549435e-38f, f * 1.0f + 1.17549435e-38f);
    float g  = -log_cr(-log_cr(uu));          // gumbel

    float w = wfull[wbase + s];
    float key;
    if (w > 0.0f) key = log_cr(fmaxf(w, 1e-30f)) + g;
    else          key = -__builtin_inff();

    uint32_t kb = __float_as_uint(key);
    kb = (kb & 0x80000000u) ? ~kb : (kb | 0x80000000u);  // monotone map
    mk[s] = kb;
  }
  atomicAdd(&asum_s, psum);
  __syncthreads();

  // ---- phase 2: num_to_mask for this row (thread 0) ----
  if (t == 0) {
    uint32_t o0, o1;
    tf2x32(kn0, kn1, 0u, (uint32_t)row, o0, o1);   // normal bits, flat idx=row
    uint32_t b = o0 ^ o1;
    float f   = u01_from_bits(b);
    float lo  = __uint_as_float(0xBF7FFFFFu);      // nextafter(-1,0)
    float u2  = fmaxf(lo, f * 2.0f + lo);          // (1 - lo) rounds to 2.0f
    float z   = erfinv_xla(u2);
    float nrm = 1.4142135623730951f * z;           // sqrt(2) as f32
    float frac = 0.15f + 0.0375f * nrm;            // MU_P + sigma*z, unfused
    float fnum = (float)asum_s * frac;
    int kk = (int)floorf(fnum);
    kk_s = kk;
    prefix_s = 0u;
    remaining_s = (uint32_t)(kk < 0 ? 0 : kk);
  }
  __syncthreads();

  // ---- phase 3: radix-select k-th largest mapped key ----
  int kk = kk_s;
  uint32_t T, r;
  if (kk <= 0)          { T = 0xFFFFFFFFu; r = 0u; }      // nothing masked
  else if (kk >= SLEN)  { T = 0u;          r = SLEN; }    // everything masked
  else {
    for (int p = 3; p >= 0; --p) {
      hist[t] = 0u;
      __syncthreads();
      uint32_t pref = prefix_s;
      uint32_t sh   = (p < 3) ? (uint32_t)(8 * (p + 1)) : 0u;
      for (int e = 0; e < EPT; ++e) {
        uint32_t m = mk[t + NTHREADS * e];
        bool act = (p == 3) || ((m >> sh) == (pref >> sh));
        if (act) atomicAdd(&hist[(m >> (8 * p)) & 0xFFu], 1u);
      }
      __syncthreads();
      if (t == 0) {
        uint32_t need = remaining_s;
        uint32_t cum = 0; int b = 255;
        for (; b > 0; --b) {
          uint32_t c = hist[b];
          if (cum + c >= need) break;
          cum += c;
        }
        prefix_s |= ((uint32_t)b) << (8 * p);
        remaining_s = need - cum;     // still to take inside chosen bin
      }
      __syncthreads();
    }
    T = prefix_s;
    r = remaining_s;                  // take first r (by index) among == T
  }

  // ---- phase 4: stable tie-break scan + write outputs ----
  const int base = t * EPT;           // contiguous chunk for index-order scan
  uint32_t mloc[EPT];
  int local_eq = 0;
  for (int e = 0; e < EPT; ++e) {
    mloc[e] = mk[base + e];
    local_eq += (mloc[e] == T) ? 1 : 0;
  }
  tscan[t] = (uint32_t)local_eq;
  __syncthreads();
  for (int off = 1; off < NTHREADS; off <<= 1) {   // Hillis-Steele inclusive
    uint32_t v = (t >= off) ? tscan[t - off] : 0u;
    __syncthreads();
    tscan[t] += v;
    __syncthreads();
  }
  uint32_t excl = tscan[t] - (uint32_t)local_eq;   // #eq before my chunk

  const int* idrow = ids + rbase;
  int* o_ids = out + rbase;
  int* o_msk = out + TOKENS_PER_OUT + rbase;
  int* o_lbl = out + 2 * TOKENS_PER_OUT + rbase;
  for (int e = 0; e < EPT; ++e) {
    int s2 = base + e;
    uint32_t m = mloc[e];
    bool eq  = (m == T);
    bool msk = (m > T) || (eq && (excl < r));
    excl += eq ? 1u : 0u;
    int id = idrow[s2];
    o_ids[s2] = msk ? 103 : id;       // MASK_ID
    o_msk[s2] = msk ? 1 : 0;
    o_lbl[s2] = msk ? -1 : 0;
  }
}

extern "C" void kernel_launch(void* const* d_in, const int* in_sizes, int n_in,
                              void* d_out, int out_size, void* d_ws, size_t ws_size,
                              hipStream_t stream) {
  (void)n_in; (void)d_ws; (void)ws_size; (void)out_size;
  const float* wfull = (const float*)d_in[0];   // my_attention_mask (B,C,2S)
  const int*   attn  = (const int*)d_in[1];     // attention_mask    (B,C,S)
  const int*   ids   = (const int*)d_in[2];     // input_ids         (B,C,S)
  int* out = (int*)d_out;

  // jax.random.key(42) -> (0,42); partitionable fold-like split:
  //   kg = enc(key,(0,0)), kn = enc(key,(0,1))
  uint32_t kg0, kg1, kn0, kn1, o0, o1;
  tf2x32(0u, 42u, 0u, 0u, o0, o1); kg0 = o0; kg1 = o1;
  tf2x32(0u, 42u, 0u, 1u, o0, o1); kn0 = o0; kn1 = o1;

  int rows = in_sizes[1] / SLEN;                // 4096
  hipLaunchKernelGGL(gumbel_topk_mask, dim3(rows), dim3(NTHREADS), 0, stream,
                     wfull, attn, ids, out, kg0, kg1, kn0, kn1);
}

// Round 2
// 203.994 us; speedup vs baseline: 1.4154x; 1.4154x over previous
//
#include <hip/hip_runtime.h>
#include <stdint.h>
#include <math.h>

#define SLEN 2048
#define EPT 8
#define NTHREADS 256
#define TOKENS_PER_OUT 8388608   // 1024*4*2048

// ---------- Threefry-2x32, 20 rounds, matches jax._src.prng ----------
__host__ __device__ __forceinline__ void tf2x32(uint32_t k0, uint32_t k1,
                                                uint32_t x0, uint32_t x1,
                                                uint32_t &o0, uint32_t &o1) {
  uint32_t ks2 = 0x1BD11BDAu ^ k0 ^ k1;
  x0 += k0; x1 += k1;
#define TFR(r) { x0 += x1; x1 = (x1 << (r)) | (x1 >> (32 - (r))); x1 ^= x0; }
  TFR(13) TFR(15) TFR(26) TFR(6)
  x0 += k1;  x1 += ks2 + 1u;
  TFR(17) TFR(29) TFR(16) TFR(24)
  x0 += ks2; x1 += k0 + 2u;
  TFR(13) TFR(15) TFR(26) TFR(6)
  x0 += k0;  x1 += k1 + 3u;
  TFR(17) TFR(29) TFR(16) TFR(24)
  x0 += k1;  x1 += ks2 + 4u;
  TFR(13) TFR(15) TFR(26) TFR(6)
  x0 += ks2; x1 += k0 + 5u;
#undef TFR
  o0 = x0; o1 = x1;
}

__device__ __forceinline__ float u01_from_bits(uint32_t bits) {
  return __uint_as_float((bits >> 9) | 0x3F800000u) - 1.0f;
}

// Correctly-rounded-quality f32 log for positive normal inputs.
// f64 atanh-form: x=2^e*m, m in [sqrt2/2,sqrt2), r=(m-1)/(m+1) (|r|<=0.1716),
// log(x)=e*ln2 + 2r*(1 + t/3 + t^2/5 + ... + t^6/13), t=r^2.
// Truncation rel err ~2^-39.5; div is IEEE-exact; no cancellation (e!=0 =>
// |result|>=0.34; e==0 => m-1 exact). Misround vs CR ~2^-14 per call.
__device__ __forceinline__ float log_cr(float x) {
  double d = (double)x;
  long long b = __double_as_longlong(d);
  int e = (int)(b >> 52) - 1023;                 // x positive normal
  double m = __longlong_as_double((b & 0x000FFFFFFFFFFFFFLL) | 0x3FF0000000000000LL);
  if (m > 1.4142135623730951) { m *= 0.5; e += 1; }
  double r = (m - 1.0) / (m + 1.0);
  double t = r * r;
  double p = 0.07692307692307693;                // 1/13
  p = fma(p, t, 0.09090909090909091);            // 1/11
  p = fma(p, t, 0.1111111111111111);             // 1/9
  p = fma(p, t, 0.14285714285714285);            // 1/7
  p = fma(p, t, 0.2);                            // 1/5
  p = fma(p, t, 0.3333333333333333);             // 1/3
  double q = fma(p, t, 1.0);
  return (float)fma((double)e, 0.6931471805599453, 2.0 * (r * q));
}

// XLA ErfInv f32 expander (Giles poly), log1p per ElementalIrEmitter::EmitLog1p
__device__ float erfinv_xla(float x) {
#pragma clang fp contract(off)
  float x2  = x * x;
  float nx2 = -x2;
  float l1p;
  if (fabsf(nx2) < 1e-4f) {
    l1p = (-0.5f * nx2 + 1.0f) * nx2;
  } else {
    l1p = log_cr(1.0f + nx2);
  }
  float w = -l1p;
  float p;
  if (w < 5.0f) {
    float ww = w - 2.5f;
    p = 2.81022636e-08f;
    p = p * ww + 3.43273939e-07f;
    p = p * ww + -3.5233877e-06f;
    p = p * ww + -4.39150654e-06f;
    p = p * ww + 0.00021858087f;
    p = p * ww + -0.00125372503f;
    p = p * ww + -0.00417768164f;
    p = p * ww + 0.246640727f;
    p = p * ww + 1.50140941f;
  } else {
    float ww = sqrtf(w) - 3.0f;
    p = -0.000200214257f;
    p = p * ww + 0.000100950558f;
    p = p * ww + 0.00134934322f;
    p = p * ww + -0.00367342844f;
    p = p * ww + 0.00573950773f;
    p = p * ww + -0.0076224613f;
    p = p * ww + 0.00943887047f;
    p = p * ww + 1.00167406f;
    p = p * ww + 2.83297682f;
  }
  return p * x;
}

__global__ __launch_bounds__(NTHREADS)
void gumbel_topk_mask(const float* __restrict__ wfull,   // (B,C,2S) f32
                      const int*   __restrict__ attn,    // (B,C,S) i32
                      const int*   __restrict__ ids,     // (B,C,S) i32
                      int* __restrict__ out,             // 3x(B,C,S) i32 concat
                      uint32_t kg0, uint32_t kg1, uint32_t kn0, uint32_t kn1) {
#pragma clang fp contract(off)
  const int row  = blockIdx.x;
  const int t    = threadIdx.x;
  const int lane = t & 63;
  const int wid  = t >> 6;

  __shared__ __align__(16) uint32_t hist[256];
  __shared__ uint32_t wsum[4];
  __shared__ int      kk_s;
  __shared__ uint32_t prefix_s;
  __shared__ uint32_t remaining_s;

  const size_t rbase = (size_t)row * SLEN;
  const size_t wbase = (size_t)row * (2 * SLEN);
  const int    base  = t * EPT;            // contiguous chunk per thread

  // ---- phase 1: vector loads + per-element keys into registers ----
  const float4* wv4 = (const float4*)(wfull + wbase + base);
  float4 w0 = wv4[0], w1 = wv4[1];
  const int4* av4 = (const int4*)(attn + rbase + base);
  int4 a0 = av4[0], a1 = av4[1];
  int psum = a0.x + a0.y + a0.z + a0.w + a1.x + a1.y + a1.z + a1.w;

  float wl[EPT] = {w0.x, w0.y, w0.z, w0.w, w1.x, w1.y, w1.z, w1.w};
  uint32_t mloc[EPT];
#pragma unroll
  for (int e = 0; e < EPT; ++e) {
    uint32_t o0, o1;
    tf2x32(kg0, kg1, 0u, (uint32_t)(rbase + base + e), o0, o1);
    float f  = u01_from_bits(o0 ^ o1);
    float uu = fmaxf(1.17549435e-38f, f * 1.0f + 1.17549435e-38f);
    float g  = -log_cr(-log_cr(uu));
    float w  = wl[e];
    float key = (w > 0.0f) ? (log_cr(fmaxf(w, 1e-30f)) + g) : -__builtin_inff();
    uint32_t kb = __float_as_uint(key);
    mloc[e] = (kb & 0x80000000u) ? ~kb : (kb | 0x80000000u);  // monotone map
  }

  // attention-sum: wave reduce, one LDS slot per wave
#pragma unroll
  for (int off = 32; off; off >>= 1) psum += __shfl_down(psum, off, 64);
  if (lane == 0) wsum[wid] = (uint32_t)psum;
  __syncthreads();

  // ---- phase 2: num_to_mask (thread 0) ----
  if (t == 0) {
    int asum = (int)(wsum[0] + wsum[1] + wsum[2] + wsum[3]);
    uint32_t o0, o1;
    tf2x32(kn0, kn1, 0u, (uint32_t)row, o0, o1);
    float f   = u01_from_bits(o0 ^ o1);
    float lo  = __uint_as_float(0xBF7FFFFFu);      // nextafter(-1,0)
    float u2  = fmaxf(lo, f * 2.0f + lo);          // (1-lo) rounds to 2.0f
    float z   = erfinv_xla(u2);
    float nrm = 1.4142135623730951f * z;
    float frac = 0.15f + 0.0375f * nrm;
    float fnum = (float)asum * frac;
    int kk = (int)floorf(fnum);
    kk_s = kk;
    prefix_s = 0u;
    remaining_s = (uint32_t)(kk < 0 ? 0 : kk);
  }
  __syncthreads();

  // ---- phase 3: radix-select k-th largest mapped key (registers only) ----
  int kk = kk_s;
  uint32_t T, r;
  if (kk <= 0)         { T = 0xFFFFFFFFu; r = 0u; }
  else if (kk >= SLEN) { T = 0u;          r = SLEN; }
  else {
    for (int p = 3; p >= 0; --p) {
      hist[t] = 0u;
      __syncthreads();
      uint32_t pref = prefix_s;
      if (p == 3) {
#pragma unroll
        for (int e = 0; e < EPT; ++e) atomicAdd(&hist[mloc[e] >> 24], 1u);
      } else {
        uint32_t sh = (uint32_t)(8 * (p + 1));
#pragma unroll
        for (int e = 0; e < EPT; ++e) {
          uint32_t m = mloc[e];
          if ((m >> sh) == (pref >> sh)) atomicAdd(&hist[(m >> (8 * p)) & 255u], 1u);
        }
      }
      __syncthreads();
      if (t < 64) {                       // wave 0: parallel bin selection
        uint32_t need = remaining_s;
        uint4 hq = ((const uint4*)hist)[t];            // bins 4t..4t+3
        uint32_t gs  = hq.x + hq.y + hq.z + hq.w;
        uint32_t sfx = gs;                             // suffix-incl over lanes
#pragma unroll
        for (int off = 1; off < 64; off <<= 1) {
          uint32_t n = __shfl_down(sfx, off, 64);
          if (t + off < 64) sfx += n;
        }
        uint32_t Gex = sfx - gs;                       // sum over lanes > t
        uint32_t S3 = Gex;
        uint32_t S2 = S3 + hq.w;
        uint32_t S1 = S2 + hq.z;
        uint32_t S0 = S1 + hq.y;
        uint32_t hh[4] = {hq.x, hq.y, hq.z, hq.w};
        uint32_t SS[4] = {S0, S1, S2, S3};
#pragma unroll
        for (int i = 0; i < 4; ++i) {
          if (hh[i] && SS[i] < need && need <= SS[i] + hh[i]) {   // unique winner
            prefix_s |= ((uint32_t)(4 * t + i)) << (8 * p);
            remaining_s = need - SS[i];
          }
        }
      }
      __syncthreads();
    }
    T = prefix_s;
    r = remaining_s;                  // take first r (by index) among == T
  }

  // ---- phase 4: stable tie-break scan (wave shuffle + 4 wave sums) ----
  int local_eq = 0;
#pragma unroll
  for (int e = 0; e < EPT; ++e) local_eq += (mloc[e] == T) ? 1 : 0;
  uint32_t v = (uint32_t)local_eq;
#pragma unroll
  for (int off = 1; off < 64; off <<= 1) {
    uint32_t n = __shfl_up(v, off, 64);
    if (lane >= off) v += n;
  }
  if (lane == 63) wsum[wid] = v;
  __syncthreads();
  uint32_t add = 0;
  for (int i = 0; i < wid; ++i) add += wsum[i];
  uint32_t excl = add + v - (uint32_t)local_eq;   // #eq before my chunk

  const int4* iv4 = (const int4*)(ids + rbase + base);
  int4 i0 = iv4[0], i1 = iv4[1];
  int idv[EPT] = {i0.x, i0.y, i0.z, i0.w, i1.x, i1.y, i1.z, i1.w};
  int oid[EPT], omk[EPT], olb[EPT];
#pragma unroll
  for (int e = 0; e < EPT; ++e) {
    uint32_t m = mloc[e];
    bool eq  = (m == T);
    bool msk = (m > T) || (eq && (excl < r));
    excl += eq ? 1u : 0u;
    oid[e] = msk ? 103 : idv[e];      // MASK_ID
    omk[e] = msk ? 1 : 0;
    olb[e] = msk ? -1 : 0;
  }
  int4* po = (int4*)(out + rbase + base);
  po[0] = make_int4(oid[0], oid[1], oid[2], oid[3]);
  po[1] = make_int4(oid[4], oid[5], oid[6], oid[7]);
  int4* pm = (int4*)(out + TOKENS_PER_OUT + rbase + base);
  pm[0] = make_int4(omk[0], omk[1], omk[2], omk[3]);
  pm[1] = make_int4(omk[4], omk[5], omk[6], omk[7]);
  int4* pl = (int4*)(out + 2 * TOKENS_PER_OUT + rbase + base);
  pl[0] = make_int4(olb[0], olb[1], olb[2], olb[3]);
  pl[1] = make_int4(olb[4], olb[5], olb[6], olb[7]);
}

extern "C" void kernel_launch(void* const* d_in, const int* in_sizes, int n_in,
                              void* d_out, int out_size, void* d_ws, size_t ws_size,
                              hipStream_t stream) {
  (void)n_in; (void)d_ws; (void)ws_size; (void)out_size;
  const float* wfull = (const float*)d_in[0];   // my_attention_mask (B,C,2S)
  const int*   attn  = (const int*)d_in[1];     // attention_mask    (B,C,S)
  const int*   ids   = (const int*)d_in[2];     // input_ids         (B,C,S)
  int* out = (int*)d_out;

  // jax.random.key(42) -> (0,42); partitionable split: kg=enc(key,(0,0)), kn=enc(key,(0,1))
  uint32_t kg0, kg1, kn0, kn1, o0, o1;
  tf2x32(0u, 42u, 0u, 0u, o0, o1); kg0 = o0; kg1 = o1;
  tf2x32(0u, 42u, 0u, 1u, o0, o1); kn0 = o0; kn1 = o1;

  int rows = in_sizes[1] / SLEN;                // 4096
  hipLaunchKernelGGL(gumbel_topk_mask, dim3(rows), dim3(NTHREADS), 0, stream,
                     wfull, attn, ids, out, kg0, kg1, kn0, kn1);
}